// Round 1
// baseline (734.101 us; speedup 1.0000x reference)
//
#include <hip/hip_runtime.h>
#include <cstdint>

constexpr int Bn = 32, Kn = 17, Hn = 192, Wn = 192, Cn = 19, Pn = 20, Sn = 10;
constexpr int HWn = Hn * Wn;
constexpr int PEAKS_FLOATS = Bn * Kn * Pn * 3;   // 32640

__constant__ int d_SKA[Cn] = {15,13,16,14,11,5,6,5,5,6,7,8,1,0,0,1,2,3,4};
__constant__ int d_SKB[Cn] = {13,11,14,12,12,11,12,6,7,8,9,10,2,1,2,3,4,5,6};

// -------- Kernel 1: 3x3 NMS peaks + top-20 per (b,k) + subpixel refine -----
__global__ __launch_bounds__(256) void topk_kernel(const float* __restrict__ heat,
                                                   float* __restrict__ out_peaks) {
    const int img = blockIdx.x;                 // b*Kn + k
    const float* __restrict__ hp = heat + (size_t)img * HWn;
    const int tid = threadIdx.x;

    // Per-thread sorted (desc) top-20 as monotonic u64 keys.
    unsigned long long cand[Pn];
#pragma unroll
    for (int j = 0; j < Pn; ++j) cand[j] = 0ULL;

    for (int idx = tid; idx < HWn; idx += 256) {
        float v = hp[idx];
        if (v <= 0.1f) continue;
        int y = idx / Wn;
        int x = idx - y * Wn;
        bool xm = (x > 0), xp = (x < Wn - 1);
        float nm = -INFINITY;
        if (y > 0) {
            const float* r0 = hp + idx - Wn;
            if (xm) nm = fmaxf(nm, r0[-1]);
            nm = fmaxf(nm, r0[0]);
            if (xp) nm = fmaxf(nm, r0[1]);
        }
        if (xm) nm = fmaxf(nm, hp[idx - 1]);
        if (xp) nm = fmaxf(nm, hp[idx + 1]);
        if (y < Hn - 1) {
            const float* r2 = hp + idx + Wn;
            if (xm) nm = fmaxf(nm, r2[-1]);
            nm = fmaxf(nm, r2[0]);
            if (xp) nm = fmaxf(nm, r2[1]);
        }
        if (v < nm) continue;   // peak iff v == 3x3 max  (v >= all neighbors)

        unsigned int u = __float_as_uint(v) | 0x80000000u;  // v > 0 -> monotonic map
        unsigned long long key =
            ((unsigned long long)u << 32) | (unsigned long long)(0xFFFFFFFFu - (unsigned)idx);
        // unrolled compare-swap insert (static indices -> stays in VGPRs)
#pragma unroll
        for (int j = 0; j < Pn; ++j) {
            if (key > cand[j]) { unsigned long long t = cand[j]; cand[j] = key; key = t; }
        }
    }

    // Spill sorted lists to LDS (padded stride 21 to spread banks)
    __shared__ unsigned long long lkeys[256 * 21];
    __shared__ unsigned long long wbest[4];
#pragma unroll
    for (int j = 0; j < Pn; ++j) lkeys[tid * 21 + j] = cand[j];
    __syncthreads();

    const int lane = tid & 63, wid = tid >> 6;
    int ptr = 0;
    for (int slot = 0; slot < Pn; ++slot) {
        unsigned long long k = (ptr < Pn) ? lkeys[tid * 21 + ptr] : 0ULL;
        unsigned long long r = k;
#pragma unroll
        for (int o = 32; o > 0; o >>= 1) {
            unsigned long long other = __shfl_xor(r, o, 64);
            if (other > r) r = other;
        }
        if (lane == 0) wbest[wid] = r;
        __syncthreads();
        unsigned long long best = wbest[0];
        if (wbest[1] > best) best = wbest[1];
        if (wbest[2] > best) best = wbest[2];
        if (wbest[3] > best) best = wbest[3];
        __syncthreads();   // protect wbest for next iteration

        if (best != 0ULL && k == best) {
            ++ptr;   // consume my entry
            unsigned int u = (unsigned int)(best >> 32);
            float v = __uint_as_float(u & 0x7FFFFFFFu);
            int idx = (int)(0xFFFFFFFFu - (unsigned int)(best & 0xFFFFFFFFu));
            int y = idx / Wn;
            int x = idx - y * Wn;
            float dx = 0.0f, dy = 0.0f;
            if (x >= 1 && x <= Wn - 2 && y >= 1 && y <= Hn - 2) {
                float rr = hp[idx + 1], ll = hp[idx - 1];
                float dd = hp[idx + Wn], uu = hp[idx - Wn];
                float dx0 = 0.5f * (rr - ll);
                float dxx = rr + ll - 2.0f * v;
                dx = (dxx != 0.0f) ? dx0 / (-dxx) : dx0;
                float dy0 = 0.5f * (dd - uu);
                float dyy = dd + uu - 2.0f * v;
                dy = (dyy != 0.0f) ? dy0 / (-dyy) : dy0;
            }
            float* o = out_peaks + ((size_t)img * Pn + slot) * 3;
            o[0] = (float)x + dx;
            o[1] = (float)y + dy;
            o[2] = v;               // v > 0.1 guaranteed -> valid
        }
        if (best == 0ULL && tid == 0) {
            float* o = out_peaks + ((size_t)img * Pn + slot) * 3;
            o[0] = 0.0f; o[1] = 0.0f; o[2] = 0.0f;
        }
    }
}

// -------- Kernel 2: PAF line-integral connection scores --------------------
__global__ __launch_bounds__(256) void conn_kernel(const float* __restrict__ paf,
                                                   const float* __restrict__ peaks,
                                                   float* __restrict__ conn) {
    const int blk = blockIdx.x;        // b*Cn + c
    const int b = blk / Cn;
    const int c = blk - b * Cn;
    const int ka = d_SKA[c], kb = d_SKB[c];
    const int tid = threadIdx.x;

    __shared__ float axs[Pn], ays[Pn], sas[Pn], bxs[Pn], bys[Pn], sbs[Pn];
    if (tid < Pn) {
        const float* pa = peaks + ((size_t)(b * Kn + ka) * Pn + tid) * 3;
        axs[tid] = pa[0]; ays[tid] = pa[1]; sas[tid] = pa[2];
        const float* pb = peaks + ((size_t)(b * Kn + kb) * Pn + tid) * 3;
        bxs[tid] = pb[0]; bys[tid] = pb[1]; sbs[tid] = pb[2];
    }
    __syncthreads();

    const float* __restrict__ pafx = paf + (size_t)(b * (2 * Cn) + 2 * c) * HWn;
    const float* __restrict__ pafy = pafx + HWn;

    for (int pair = tid; pair < Pn * Pn; pair += 256) {
        int i = pair / Pn;           // index into A-peaks
        int j = pair - i * Pn;       // index into B-peaks
        float ax = axs[i], ay = ays[i], sa = sas[i];
        float bx = bxs[j], by = bys[j], sb = sbs[j];
        float dxl = bx - ax, dyl = by - ay;
        float norm = sqrtf(dxl * dxl + dyl * dyl) + 1e-8f;
        float vx = dxl / norm, vy = dyl / norm;

        float sum = 0.0f;
        int cnt = 0, pos = 0;
#pragma unroll
        for (int s = 0; s < Sn; ++s) {
            float t = (s == Sn - 1) ? 1.0f : (float)s * (1.0f / 9.0f);
            float xs = ax + dxl * t;
            float ys = ay + dyl * t;
            int xi = (int)xs;        // trunc toward zero == astype(int32)
            int yi = (int)ys;
            bool inb = (xi >= 0) && (xi < Wn) && (yi >= 0) && (yi < Hn);
            int xc = min(max(xi, 0), Wn - 1);
            int yc = min(max(yi, 0), Hn - 1);
            int idx = yc * Wn + xc;
            float pxv = pafx[idx];
            float pyv = pafy[idx];
            float vs = pxv * vx + pyv * vy;
            if (inb) {
                ++cnt;
                sum += vs;
                if (vs > 0.05f) ++pos;
            }
        }
        float denom = fmaxf((float)cnt, 1.0f);
        float mean = sum / denom;
        float ratio = (float)pos / denom;
        bool ok = (cnt > 0) && (mean > 0.0f) && (ratio > 0.8f) && (sa > 0.1f) && (sb > 0.1f);
        conn[(size_t)blk * (Pn * Pn) + pair] = ok ? (mean + 0.5f * (sa + sb)) : 0.0f;
    }
}

extern "C" void kernel_launch(void* const* d_in, const int* in_sizes, int n_in,
                              void* d_out, int out_size, void* d_ws, size_t ws_size,
                              hipStream_t stream) {
    const float* heat = (const float*)d_in[0];
    const float* paf  = (const float*)d_in[1];
    float* out   = (float*)d_out;
    float* peaks = out;                    // (B,K,P,3)
    float* conn  = out + PEAKS_FLOATS;     // (B,C,P,P)

    topk_kernel<<<Bn * Kn, 256, 0, stream>>>(heat, peaks);
    conn_kernel<<<Bn * Cn, 256, 0, stream>>>(paf, peaks, conn);
}

// Round 3
// 570.733 us; speedup vs baseline: 1.2862x; 1.2862x over previous
//
#include <hip/hip_runtime.h>
#include <cstdint>

constexpr int Bn = 32, Kn = 17, Hn = 192, Wn = 192, Cn = 19, Pn = 20, Sn = 10;
constexpr int HWn = Hn * Wn;
constexpr int NSTRIP = 4, STRIPROWS = Hn / NSTRIP;       // 48 rows per strip
constexpr int PIX_PER_THREAD = STRIPROWS * Wn / 256;     // 36
constexpr int PEAKS_FLOATS = Bn * Kn * Pn * 3;           // 32640
constexpr int NPAIR = Pn * Pn;                           // 400

__constant__ int d_SKA[Cn] = {15,13,16,14,11,5,6,5,5,6,7,8,1,0,0,1,2,3,4};
__constant__ int d_SKB[Cn] = {13,11,14,12,12,11,12,6,7,8,9,10,2,1,2,3,4,5,6};

// ---- Stage 1: per-strip 3x3-NMS peaks + strip top-20 (register-only merge) -
__global__ __launch_bounds__(256, 4) void topk_strip(const float* __restrict__ heat,
                                                     unsigned long long* __restrict__ strip_out) {
    const int img = blockIdx.x >> 2;
    const int strip = blockIdx.x & 3;
    const float* __restrict__ hp = heat + (size_t)img * HWn;
    const int tid = threadIdx.x;
    const int base = strip * STRIPROWS * Wn;

    unsigned long long cand[Pn];
#pragma unroll
    for (int j = 0; j < Pn; ++j) cand[j] = 0ULL;

#pragma unroll 1
    for (int r = 0; r < PIX_PER_THREAD; ++r) {
        const int idx = base + r * 256 + tid;
        float v = hp[idx];
        if (v <= 0.1f) continue;
        int y = idx / Wn;
        int x = idx - y * Wn;
        bool xm = (x > 0), xp = (x < Wn - 1);
        float nm = -INFINITY;
        if (y > 0) {
            const float* r0 = hp + idx - Wn;
            if (xm) nm = fmaxf(nm, r0[-1]);
            nm = fmaxf(nm, r0[0]);
            if (xp) nm = fmaxf(nm, r0[1]);
        }
        if (xm) nm = fmaxf(nm, hp[idx - 1]);
        if (xp) nm = fmaxf(nm, hp[idx + 1]);
        if (y < Hn - 1) {
            const float* r2 = hp + idx + Wn;
            if (xm) nm = fmaxf(nm, r2[-1]);
            nm = fmaxf(nm, r2[0]);
            if (xp) nm = fmaxf(nm, r2[1]);
        }
        if (v < nm) continue;   // peak iff v == 3x3 max

        unsigned int u = __float_as_uint(v) | 0x80000000u;  // v>0 -> monotonic
        unsigned long long key =
            ((unsigned long long)u << 32) | (unsigned long long)(0xFFFFFFFFu - (unsigned)idx);
#pragma unroll
        for (int j = 0; j < Pn; ++j) {
            if (key > cand[j]) { unsigned long long t = cand[j]; cand[j] = key; key = t; }
        }
    }

    // Block-wide top-20 extraction; per-thread lists stay in registers.
    __shared__ unsigned long long wmax[4];
    const int lane = tid & 63, wid = tid >> 6;
    unsigned long long* out = strip_out + (size_t)blockIdx.x * Pn;

#pragma unroll 1
    for (int slot = 0; slot < Pn; ++slot) {
        unsigned long long r = cand[0];
#pragma unroll
        for (int o = 32; o > 0; o >>= 1) {
            unsigned long long other = __shfl_xor(r, o, 64);
            if (other > r) r = other;
        }
        if (lane == 0) wmax[wid] = r;
        __syncthreads();
        unsigned long long best = wmax[0];
        if (wmax[1] > best) best = wmax[1];
        if (wmax[2] > best) best = wmax[2];
        if (wmax[3] > best) best = wmax[3];
        __syncthreads();

        if (best != 0ULL && cand[0] == best) {   // unique owner (keys unique)
#pragma unroll
            for (int j = 0; j < Pn - 1; ++j) cand[j] = cand[j + 1];
            cand[Pn - 1] = 0ULL;
            out[slot] = best;
        }
        if (best == 0ULL && tid == 0) out[slot] = 0ULL;
    }
}

// ---- Stage 2: merge 4 strip lists -> image top-20 + subpixel refine --------
__global__ __launch_bounds__(64) void topk_merge(const float* __restrict__ heat,
                                                 const unsigned long long* __restrict__ strip_out,
                                                 float* __restrict__ out_peaks) {
    const int img = blockIdx.x;
    const int t = threadIdx.x;
    const unsigned long long* sp = strip_out + (size_t)img * (NSTRIP * Pn);
    unsigned long long key0 = sp[t];
    unsigned long long key1 = (t < NSTRIP * Pn - 64) ? sp[64 + t] : 0ULL;
    const float* __restrict__ hp = heat + (size_t)img * HWn;

#pragma unroll 1
    for (int slot = 0; slot < Pn; ++slot) {
        unsigned long long m = (key0 > key1) ? key0 : key1;
        unsigned long long r = m;
#pragma unroll
        for (int o = 32; o > 0; o >>= 1) {
            unsigned long long other = __shfl_xor(r, o, 64);
            if (other > r) r = other;
        }
        // r = block max, identical on all lanes
        if (r != 0ULL && m == r) {               // unique owner
            if (key0 == r) { key0 = key1; key1 = 0ULL; } else { key1 = 0ULL; }
            unsigned int u = (unsigned int)(r >> 32);
            float v = __uint_as_float(u & 0x7FFFFFFFu);
            int idx = (int)(0xFFFFFFFFu - (unsigned int)(r & 0xFFFFFFFFu));
            int y = idx / Wn;
            int x = idx - y * Wn;
            float dx = 0.0f, dy = 0.0f;
            if (x >= 1 && x <= Wn - 2 && y >= 1 && y <= Hn - 2) {
                float rr = hp[idx + 1], ll = hp[idx - 1];
                float dd = hp[idx + Wn], uu = hp[idx - Wn];
                float dx0 = 0.5f * (rr - ll);
                float dxx = rr + ll - 2.0f * v;
                dx = (dxx != 0.0f) ? dx0 / (-dxx) : dx0;
                float dy0 = 0.5f * (dd - uu);
                float dyy = dd + uu - 2.0f * v;
                dy = (dyy != 0.0f) ? dy0 / (-dyy) : dy0;
            }
            float* o = out_peaks + ((size_t)img * Pn + slot) * 3;
            o[0] = (float)x + dx;
            o[1] = (float)y + dy;
            o[2] = v;
        }
        if (r == 0ULL && t == 0) {
            float* o = out_peaks + ((size_t)img * Pn + slot) * 3;
            o[0] = 0.0f; o[1] = 0.0f; o[2] = 0.0f;
        }
    }
}

// ---- Stage 3: PAF line-integral connection scores (1 pair per thread) ------
__global__ __launch_bounds__(256) void conn_kernel(const float* __restrict__ paf,
                                                   const float* __restrict__ peaks,
                                                   float* __restrict__ conn) {
    const int e = blockIdx.x * 256 + threadIdx.x;
    if (e >= Bn * Cn * NPAIR) return;
    const int bc = e / NPAIR;
    const int pair = e - bc * NPAIR;
    const int b = bc / Cn;
    const int c = bc - b * Cn;
    const int i = pair / Pn;
    const int j = pair - i * Pn;
    const int ka = d_SKA[c], kb = d_SKB[c];

    const float* pa = peaks + ((size_t)(b * Kn + ka) * Pn + i) * 3;
    const float* pb = peaks + ((size_t)(b * Kn + kb) * Pn + j) * 3;
    float ax = pa[0], ay = pa[1], sa = pa[2];
    float bx = pb[0], by = pb[1], sb = pb[2];

    const float* __restrict__ pafx = paf + (size_t)(b * (2 * Cn) + 2 * c) * HWn;
    const float* __restrict__ pafy = pafx + HWn;

    float dxl = bx - ax, dyl = by - ay;
    float norm = sqrtf(dxl * dxl + dyl * dyl) + 1e-8f;
    float vx = dxl / norm, vy = dyl / norm;

    float sum = 0.0f;
    int cnt = 0, pos = 0;
#pragma unroll
    for (int s = 0; s < Sn; ++s) {
        float t = (s == Sn - 1) ? 1.0f : (float)s * (1.0f / 9.0f);
        float xs = ax + dxl * t;
        float ys = ay + dyl * t;
        int xi = (int)xs;            // trunc toward zero == astype(int32)
        int yi = (int)ys;
        bool inb = (xi >= 0) && (xi < Wn) && (yi >= 0) && (yi < Hn);
        int xc = min(max(xi, 0), Wn - 1);
        int yc = min(max(yi, 0), Hn - 1);
        int idx = yc * Wn + xc;
        float pxv = pafx[idx];
        float pyv = pafy[idx];
        float vs = pxv * vx + pyv * vy;
        if (inb) {
            ++cnt;
            sum += vs;
            if (vs > 0.05f) ++pos;
        }
    }
    float denom = fmaxf((float)cnt, 1.0f);
    float mean = sum / denom;
    float ratio = (float)pos / denom;
    bool ok = (cnt > 0) && (mean > 0.0f) && (ratio > 0.8f) && (sa > 0.1f) && (sb > 0.1f);
    conn[(size_t)bc * NPAIR + pair] = ok ? (mean + 0.5f * (sa + sb)) : 0.0f;
}

extern "C" void kernel_launch(void* const* d_in, const int* in_sizes, int n_in,
                              void* d_out, int out_size, void* d_ws, size_t ws_size,
                              hipStream_t stream) {
    const float* heat = (const float*)d_in[0];
    const float* paf  = (const float*)d_in[1];
    float* out   = (float*)d_out;
    float* peaks = out;                    // (B,K,P,3)
    float* conn  = out + PEAKS_FLOATS;     // (B,C,P,P)
    unsigned long long* strips = (unsigned long long*)d_ws;  // 544*4*20 u64 = 348 KB

    topk_strip<<<Bn * Kn * NSTRIP, 256, 0, stream>>>(heat, strips);
    topk_merge<<<Bn * Kn, 64, 0, stream>>>(heat, strips, peaks);
    conn_kernel<<<(Bn * Cn * NPAIR + 255) / 256, 256, 0, stream>>>(paf, peaks, conn);
}

// Round 4
// 389.042 us; speedup vs baseline: 1.8869x; 1.4670x over previous
//
#include <hip/hip_runtime.h>
#include <cstdint>

constexpr int Bn = 32, Kn = 17, Hn = 192, Wn = 192, Cn = 19, Pn = 20, Sn = 10;
constexpr int HWn = Hn * Wn;
constexpr int NSTRIP = 4, STRIPROWS = Hn / NSTRIP;       // 48 rows per strip
constexpr int PEAKS_FLOATS = Bn * Kn * Pn * 3;           // 32640
constexpr int NPAIR = Pn * Pn;                           // 400
constexpr int STK = 19;                                  // per-thread peak stack cap
constexpr int CH_ROWS = 48, CH_PIX = CH_ROWS * Wn;       // conn chunk: 9216 px

__constant__ int d_SKA[Cn] = {15,13,16,14,11,5,6,5,5,6,7,8,1,0,0,1,2,3,4};
__constant__ int d_SKB[Cn] = {13,11,14,12,12,11,12,6,7,8,9,10,2,1,2,3,4,5,6};

__device__ __forceinline__ float m3(float a, float b, float c) {
    return fmaxf(fmaxf(a, b), c);
}

// ---- Stage 1: per-strip 3x3-NMS peaks + strip top-20 ----------------------
// float4-quad scan, LDS peak stack, deferred sorted insert, register merge.
__global__ __launch_bounds__(256, 4) void topk_strip(const float* __restrict__ heat,
                                                     unsigned long long* __restrict__ strip_out) {
    const int img = blockIdx.x >> 2;
    const int strip = blockIdx.x & 3;
    const float* __restrict__ hp = heat + (size_t)img * HWn;
    const int tid = threadIdx.x;

    __shared__ unsigned long long stack[256 * STK];   // 38912 B
    __shared__ unsigned long long wmax[4];
    const int sbase = tid * STK;
    int scnt = 0;

#pragma unroll 1
    for (int it = 0; it < 9; ++it) {
        const int q = it * 256 + tid;          // 0..2303: 48 rows x 48 quads
        const int ry = q / 48;
        const int qx = q - ry * 48;
        const int gy = strip * STRIPROWS + ry;
        const int x0 = qx * 4;
        const float* rp = hp + gy * Wn + x0;

        const bool hl = x0 > 0, hr = x0 < Wn - 4;
        float4 cc = *(const float4*)rp;
        float cl = hl ? rp[-1] : -INFINITY;
        float cr = hr ? rp[4] : -INFINITY;

        float4 tt = make_float4(-INFINITY, -INFINITY, -INFINITY, -INFINITY);
        float tl = -INFINITY, tr = -INFINITY;
        if (gy > 0) {
            tt = *(const float4*)(rp - Wn);
            if (hl) tl = rp[-Wn - 1];
            if (hr) tr = rp[-Wn + 4];
        }
        float4 bb = make_float4(-INFINITY, -INFINITY, -INFINITY, -INFINITY);
        float bl = -INFINITY, br = -INFINITY;
        if (gy < Hn - 1) {
            bb = *(const float4*)(rp + Wn);
            if (hl) bl = rp[Wn - 1];
            if (hr) br = rp[Wn + 4];
        }

        // horizontal 3-max per row, then vertical 3-max (self included)
        float n0 = m3(m3(tl, tt.x, tt.y), m3(cl, cc.x, cc.y), m3(bl, bb.x, bb.y));
        float n1 = m3(m3(tt.x, tt.y, tt.z), m3(cc.x, cc.y, cc.z), m3(bb.x, bb.y, bb.z));
        float n2 = m3(m3(tt.y, tt.z, tt.w), m3(cc.y, cc.z, cc.w), m3(bb.y, bb.z, bb.w));
        float n3 = m3(m3(tt.z, tt.w, tr), m3(cc.z, cc.w, cr), m3(bb.z, bb.w, br));

        const int pidx = gy * Wn + x0;
#pragma unroll
        for (int i = 0; i < 4; ++i) {
            float v = (i == 0) ? cc.x : (i == 1) ? cc.y : (i == 2) ? cc.z : cc.w;
            float nm = (i == 0) ? n0 : (i == 1) ? n1 : (i == 2) ? n2 : n3;
            if (v > 0.1f && v >= nm && scnt < STK) {
                unsigned int u = __float_as_uint(v) | 0x80000000u;   // v>0 -> monotonic
                unsigned long long key = ((unsigned long long)u << 32) |
                                         (unsigned long long)(0xFFFFFFFFu - (unsigned)(pidx + i));
                stack[sbase + scnt] = key;
                ++scnt;
            }
        }
    }

    // Deferred: insert stacked peaks into per-thread sorted top-20 (registers)
    unsigned long long cand[Pn];
#pragma unroll
    for (int j = 0; j < Pn; ++j) cand[j] = 0ULL;
#pragma unroll 1
    for (int e = 0; e < scnt; ++e) {
        unsigned long long key = stack[sbase + e];
#pragma unroll
        for (int j = 0; j < Pn; ++j) {
            if (key > cand[j]) { unsigned long long t = cand[j]; cand[j] = key; key = t; }
        }
    }
    __syncthreads();

    // Block-wide top-20 extraction
    const int lane = tid & 63, wid = tid >> 6;
    unsigned long long* out = strip_out + (size_t)blockIdx.x * Pn;

#pragma unroll 1
    for (int slot = 0; slot < Pn; ++slot) {
        unsigned long long r = cand[0];
#pragma unroll
        for (int o = 32; o > 0; o >>= 1) {
            unsigned long long other = __shfl_xor(r, o, 64);
            if (other > r) r = other;
        }
        if (lane == 0) wmax[wid] = r;
        __syncthreads();
        unsigned long long best = wmax[0];
        if (wmax[1] > best) best = wmax[1];
        if (wmax[2] > best) best = wmax[2];
        if (wmax[3] > best) best = wmax[3];
        __syncthreads();

        if (best != 0ULL && cand[0] == best) {   // unique owner (keys unique)
#pragma unroll
            for (int j = 0; j < Pn - 1; ++j) cand[j] = cand[j + 1];
            cand[Pn - 1] = 0ULL;
            out[slot] = best;
        }
        if (best == 0ULL && tid == 0) out[slot] = 0ULL;
    }
}

// ---- Stage 2: merge 4 strip lists -> image top-20 + subpixel refine --------
__global__ __launch_bounds__(64) void topk_merge(const float* __restrict__ heat,
                                                 const unsigned long long* __restrict__ strip_out,
                                                 float* __restrict__ out_peaks) {
    const int img = blockIdx.x;
    const int t = threadIdx.x;
    const unsigned long long* sp = strip_out + (size_t)img * (NSTRIP * Pn);
    unsigned long long key0 = sp[t];
    unsigned long long key1 = (t < NSTRIP * Pn - 64) ? sp[64 + t] : 0ULL;
    const float* __restrict__ hp = heat + (size_t)img * HWn;

#pragma unroll 1
    for (int slot = 0; slot < Pn; ++slot) {
        unsigned long long m = (key0 > key1) ? key0 : key1;
        unsigned long long r = m;
#pragma unroll
        for (int o = 32; o > 0; o >>= 1) {
            unsigned long long other = __shfl_xor(r, o, 64);
            if (other > r) r = other;
        }
        if (r != 0ULL && m == r) {               // unique owner
            if (key0 == r) { key0 = key1; key1 = 0ULL; } else { key1 = 0ULL; }
            unsigned int u = (unsigned int)(r >> 32);
            float v = __uint_as_float(u & 0x7FFFFFFFu);
            int idx = (int)(0xFFFFFFFFu - (unsigned int)(r & 0xFFFFFFFFu));
            int y = idx / Wn;
            int x = idx - y * Wn;
            float dx = 0.0f, dy = 0.0f;
            if (x >= 1 && x <= Wn - 2 && y >= 1 && y <= Hn - 2) {
                float rr = hp[idx + 1], ll = hp[idx - 1];
                float dd = hp[idx + Wn], uu = hp[idx - Wn];
                float dx0 = 0.5f * (rr - ll);
                float dxx = rr + ll - 2.0f * v;
                dx = (dxx != 0.0f) ? dx0 / (-dxx) : dx0;
                float dy0 = 0.5f * (dd - uu);
                float dyy = dd + uu - 2.0f * v;
                dy = (dyy != 0.0f) ? dy0 / (-dyy) : dy0;
            }
            float* o = out_peaks + ((size_t)img * Pn + slot) * 3;
            o[0] = (float)x + dx;
            o[1] = (float)y + dy;
            o[2] = v;
        }
        if (r == 0ULL && t == 0) {
            float* o = out_peaks + ((size_t)img * Pn + slot) * 3;
            o[0] = 0.0f; o[1] = 0.0f; o[2] = 0.0f;
        }
    }
}

// ---- Stage 3: PAF connection scores, LDS-staged coalesced -----------------
__global__ __launch_bounds__(512, 2) void conn_staged(const float* __restrict__ paf,
                                                      const float* __restrict__ peaks,
                                                      float* __restrict__ conn) {
    __shared__ float sx[CH_PIX];
    __shared__ float sy[CH_PIX];
    const int bc = blockIdx.x;         // b*Cn + c
    const int b = bc / Cn;
    const int c = bc - b * Cn;
    const int tid = threadIdx.x;
    const float* __restrict__ pafx = paf + (size_t)(b * (2 * Cn) + 2 * c) * HWn;
    const float* __restrict__ pafy = pafx + HWn;

    const bool act = tid < NPAIR;
    float vx = 0.0f, vy = 0.0f, sa = 0.0f, sb = 0.0f;
    int sidx[Sn];
    bool sin_[Sn];
    if (act) {
        const int i = tid / Pn, j = tid - (tid / Pn) * Pn;
        const int ka = d_SKA[c], kb = d_SKB[c];
        const float* pa = peaks + ((size_t)(b * Kn + ka) * Pn + i) * 3;
        const float* pb = peaks + ((size_t)(b * Kn + kb) * Pn + j) * 3;
        float ax = pa[0], ay = pa[1];
        sa = pa[2];
        float bx = pb[0], by = pb[1];
        sb = pb[2];
        float dxl = bx - ax, dyl = by - ay;
        float norm = sqrtf(dxl * dxl + dyl * dyl) + 1e-8f;
        vx = dxl / norm;
        vy = dyl / norm;
#pragma unroll
        for (int s = 0; s < Sn; ++s) {
            float t = (s == Sn - 1) ? 1.0f : (float)s * (1.0f / 9.0f);
            float xs = ax + dxl * t;
            float ys = ay + dyl * t;
            int xi = (int)xs;            // trunc toward zero == astype(int32)
            int yi = (int)ys;
            sin_[s] = (xi >= 0) && (xi < Wn) && (yi >= 0) && (yi < Hn);
            int xc = min(max(xi, 0), Wn - 1);
            int yc = min(max(yi, 0), Hn - 1);
            sidx[s] = yc * Wn + xc;
        }
    } else {
#pragma unroll
        for (int s = 0; s < Sn; ++s) { sidx[s] = 0; sin_[s] = false; }
    }

    float sum = 0.0f;
    int cnt = 0, pos = 0;
#pragma unroll 1
    for (int ch = 0; ch < Hn / CH_ROWS; ++ch) {
        const int r0 = ch * CH_PIX;
        const float4* gx = (const float4*)(pafx + r0);
        const float4* gy = (const float4*)(pafy + r0);
        float4* lx = (float4*)sx;
        float4* ly = (float4*)sy;
        for (int k = tid; k < CH_PIX / 4; k += 512) {
            lx[k] = gx[k];
            ly[k] = gy[k];
        }
        __syncthreads();
        if (act) {
#pragma unroll
            for (int s = 0; s < Sn; ++s) {
                int rel = sidx[s] - r0;
                if (sin_[s] && rel >= 0 && rel < CH_PIX) {
                    float vs = sx[rel] * vx + sy[rel] * vy;
                    ++cnt;
                    sum += vs;
                    if (vs > 0.05f) ++pos;
                }
            }
        }
        __syncthreads();
    }

    if (act) {
        float denom = fmaxf((float)cnt, 1.0f);
        float mean = sum / denom;
        float ratio = (float)pos / denom;
        bool ok = (cnt > 0) && (mean > 0.0f) && (ratio > 0.8f) && (sa > 0.1f) && (sb > 0.1f);
        conn[(size_t)bc * NPAIR + tid] = ok ? (mean + 0.5f * (sa + sb)) : 0.0f;
    }
}

extern "C" void kernel_launch(void* const* d_in, const int* in_sizes, int n_in,
                              void* d_out, int out_size, void* d_ws, size_t ws_size,
                              hipStream_t stream) {
    const float* heat = (const float*)d_in[0];
    const float* paf  = (const float*)d_in[1];
    float* out   = (float*)d_out;
    float* peaks = out;                    // (B,K,P,3)
    float* conn  = out + PEAKS_FLOATS;     // (B,C,P,P)
    unsigned long long* strips = (unsigned long long*)d_ws;  // 544*4*20 u64

    topk_strip<<<Bn * Kn * NSTRIP, 256, 0, stream>>>(heat, strips);
    topk_merge<<<Bn * Kn, 64, 0, stream>>>(heat, strips, peaks);
    conn_staged<<<Bn * Cn, 512, 0, stream>>>(paf, peaks, conn);
}

// Round 5
// 367.475 us; speedup vs baseline: 1.9977x; 1.0587x over previous
//
#include <hip/hip_runtime.h>
#include <cstdint>

constexpr int Bn = 32, Kn = 17, Hn = 192, Wn = 192, Cn = 19, Pn = 20, Sn = 10;
constexpr int HWn = Hn * Wn;
constexpr int NSTRIP = 4, STRIPROWS = Hn / NSTRIP;       // 48 rows per strip
constexpr int PEAKS_FLOATS = Bn * Kn * Pn * 3;           // 32640
constexpr int NPAIR = Pn * Pn;                           // 400
constexpr int STK = 19;                                  // per-thread peak stack cap
constexpr int CH_ROWS = 32, CH_PIX = CH_ROWS * Wn;       // conn chunk: 6144 px
constexpr int NCH = Hn / CH_ROWS;                        // 6 chunks

__constant__ int d_SKA[Cn] = {15,13,16,14,11,5,6,5,5,6,7,8,1,0,0,1,2,3,4};
__constant__ int d_SKB[Cn] = {13,11,14,12,12,11,12,6,7,8,9,10,2,1,2,3,4,5,6};

__device__ __forceinline__ float m3(float a, float b, float c) {
    return fmaxf(fmaxf(a, b), c);
}

// ---- Stage 1: per-strip 3x3-NMS + per-WAVE top-20, barrier-free -----------
__global__ __launch_bounds__(256, 4) void topk_strip(const float* __restrict__ heat,
                                                     unsigned long long* __restrict__ wave_out) {
    const int img = blockIdx.x >> 2;
    const int strip = blockIdx.x & 3;
    const float* __restrict__ hp = heat + (size_t)img * HWn;
    const int tid = threadIdx.x;

    __shared__ unsigned long long stack[256 * STK];   // 38912 B, per-thread regions
    const int sbase = tid * STK;
    int scnt = 0;
    unsigned long long cmax = 0ULL;                   // running max of my stack
    int cpos = 0;                                     // its slot

#pragma unroll 1
    for (int it = 0; it < 9; ++it) {
        const int q = it * 256 + tid;          // 0..2303: 48 rows x 48 quads
        const int ry = q / 48;
        const int qx = q - ry * 48;
        const int gy = strip * STRIPROWS + ry;
        const int x0 = qx * 4;
        const float* rp = hp + gy * Wn + x0;

        const bool hl = x0 > 0, hr = x0 < Wn - 4;
        float4 cc = *(const float4*)rp;
        float cl = hl ? rp[-1] : -INFINITY;
        float cr = hr ? rp[4] : -INFINITY;

        float4 tt = make_float4(-INFINITY, -INFINITY, -INFINITY, -INFINITY);
        float tl = -INFINITY, tr = -INFINITY;
        if (gy > 0) {
            tt = *(const float4*)(rp - Wn);
            if (hl) tl = rp[-Wn - 1];
            if (hr) tr = rp[-Wn + 4];
        }
        float4 bb = make_float4(-INFINITY, -INFINITY, -INFINITY, -INFINITY);
        float bl = -INFINITY, br = -INFINITY;
        if (gy < Hn - 1) {
            bb = *(const float4*)(rp + Wn);
            if (hl) bl = rp[Wn - 1];
            if (hr) br = rp[Wn + 4];
        }

        float n0 = m3(m3(tl, tt.x, tt.y), m3(cl, cc.x, cc.y), m3(bl, bb.x, bb.y));
        float n1 = m3(m3(tt.x, tt.y, tt.z), m3(cc.x, cc.y, cc.z), m3(bb.x, bb.y, bb.z));
        float n2 = m3(m3(tt.y, tt.z, tt.w), m3(cc.y, cc.z, cc.w), m3(bb.y, bb.z, bb.w));
        float n3 = m3(m3(tt.z, tt.w, tr), m3(cc.z, cc.w, cr), m3(bb.z, bb.w, br));

        const int pidx = gy * Wn + x0;
#pragma unroll
        for (int i = 0; i < 4; ++i) {
            float v = (i == 0) ? cc.x : (i == 1) ? cc.y : (i == 2) ? cc.z : cc.w;
            float nm = (i == 0) ? n0 : (i == 1) ? n1 : (i == 2) ? n2 : n3;
            if (v > 0.1f && v >= nm && scnt < STK) {
                unsigned int u = __float_as_uint(v) | 0x80000000u;   // v>0 -> monotonic
                unsigned long long key = ((unsigned long long)u << 32) |
                                         (unsigned long long)(0xFFFFFFFFu - (unsigned)(pidx + i));
                stack[sbase + scnt] = key;
                if (key > cmax) { cmax = key; cpos = scnt; }
                ++scnt;
            }
        }
    }

    // Per-wave top-20 extraction (no barriers, keys globally unique)
    const int lane = tid & 63, wid = tid >> 6;
    unsigned long long* out = wave_out + ((size_t)blockIdx.x * 4 + wid) * Pn;

#pragma unroll 1
    for (int slot = 0; slot < Pn; ++slot) {
        unsigned long long r = cmax;
#pragma unroll
        for (int o = 32; o > 0; o >>= 1) {
            unsigned long long t = __shfl_xor(r, o, 64);
            if (t > r) r = t;
        }
        if (r != 0ULL && cmax == r) {        // unique owner: remove + rescan
            --scnt;
            stack[sbase + cpos] = stack[sbase + scnt];
            cmax = 0ULL; cpos = 0;
            for (int e = 0; e < scnt; ++e) {
                unsigned long long k2 = stack[sbase + e];
                if (k2 > cmax) { cmax = k2; cpos = e; }
            }
        }
        if (lane == 0) out[slot] = r;
    }
}

// ---- Stage 2: merge 16 wave lists (320 keys) -> image top-20 + refine -----
__global__ __launch_bounds__(64) void topk_merge(const float* __restrict__ heat,
                                                 const unsigned long long* __restrict__ wave_out,
                                                 float* __restrict__ out_peaks) {
    const int img = blockIdx.x;
    const int t = threadIdx.x;
    const unsigned long long* sp = wave_out + (size_t)img * (NSTRIP * 4 * Pn);
    unsigned long long k0 = sp[t];
    unsigned long long k1 = sp[t + 64];
    unsigned long long k2 = sp[t + 128];
    unsigned long long k3 = sp[t + 192];
    unsigned long long k4 = sp[t + 256];
    const float* __restrict__ hp = heat + (size_t)img * HWn;

    unsigned long long mine = 0ULL;
#pragma unroll 1
    for (int slot = 0; slot < Pn; ++slot) {
        unsigned long long m = k0;
        if (k1 > m) m = k1;
        if (k2 > m) m = k2;
        if (k3 > m) m = k3;
        if (k4 > m) m = k4;
        unsigned long long r = m;
#pragma unroll
        for (int o = 32; o > 0; o >>= 1) {
            unsigned long long x = __shfl_xor(r, o, 64);
            if (x > r) r = x;
        }
        if (r != 0ULL && m == r) {           // unique owner: remove one instance
            if (k0 == r)      { k0 = k1; k1 = k2; k2 = k3; k3 = k4; k4 = 0ULL; }
            else if (k1 == r) { k1 = k2; k2 = k3; k3 = k4; k4 = 0ULL; }
            else if (k2 == r) { k2 = k3; k3 = k4; k4 = 0ULL; }
            else if (k3 == r) { k3 = k4; k4 = 0ULL; }
            else              { k4 = 0ULL; }
        }
        if (t == slot) mine = r;
    }

    if (t < Pn) {
        float* o = out_peaks + ((size_t)img * Pn + t) * 3;
        if (mine == 0ULL) {
            o[0] = 0.0f; o[1] = 0.0f; o[2] = 0.0f;
        } else {
            unsigned int u = (unsigned int)(mine >> 32);
            float v = __uint_as_float(u & 0x7FFFFFFFu);
            int idx = (int)(0xFFFFFFFFu - (unsigned int)(mine & 0xFFFFFFFFu));
            int y = idx / Wn;
            int x = idx - y * Wn;
            float dx = 0.0f, dy = 0.0f;
            if (x >= 1 && x <= Wn - 2 && y >= 1 && y <= Hn - 2) {
                float rr = hp[idx + 1], ll = hp[idx - 1];
                float dd = hp[idx + Wn], uu = hp[idx - Wn];
                float dx0 = 0.5f * (rr - ll);
                float dxx = rr + ll - 2.0f * v;
                dx = (dxx != 0.0f) ? dx0 / (-dxx) : dx0;
                float dy0 = 0.5f * (dd - uu);
                float dyy = dd + uu - 2.0f * v;
                dy = (dyy != 0.0f) ? dy0 / (-dyy) : dy0;
            }
            o[0] = (float)x + dx;
            o[1] = (float)y + dy;
            o[2] = v;
        }
    }
}

// ---- Stage 3: PAF connection scores, LDS-staged coalesced -----------------
__global__ __launch_bounds__(512, 3) void conn_staged(const float* __restrict__ paf,
                                                      const float* __restrict__ peaks,
                                                      float* __restrict__ conn) {
    __shared__ float sx[CH_PIX];
    __shared__ float sy[CH_PIX];
    const int bc = blockIdx.x;         // b*Cn + c
    const int b = bc / Cn;
    const int c = bc - b * Cn;
    const int tid = threadIdx.x;
    const float* __restrict__ pafx = paf + (size_t)(b * (2 * Cn) + 2 * c) * HWn;
    const float* __restrict__ pafy = pafx + HWn;

    const bool act = tid < NPAIR;
    float vx = 0.0f, vy = 0.0f, sa = 0.0f, sb = 0.0f;
    int cnt = 0;
    int sidx[Sn];
    if (act) {
        const int i = tid / Pn, j = tid - (tid / Pn) * Pn;
        const int ka = d_SKA[c], kb = d_SKB[c];
        const float* pa = peaks + ((size_t)(b * Kn + ka) * Pn + i) * 3;
        const float* pb = peaks + ((size_t)(b * Kn + kb) * Pn + j) * 3;
        float ax = pa[0], ay = pa[1];
        sa = pa[2];
        float bx = pb[0], by = pb[1];
        sb = pb[2];
        float dxl = bx - ax, dyl = by - ay;
        float norm = sqrtf(dxl * dxl + dyl * dyl) + 1e-8f;
        vx = dxl / norm;
        vy = dyl / norm;
#pragma unroll
        for (int s = 0; s < Sn; ++s) {
            float t = (s == Sn - 1) ? 1.0f : (float)s * (1.0f / 9.0f);
            float xs = ax + dxl * t;
            float ys = ay + dyl * t;
            int xi = (int)xs;            // trunc toward zero == astype(int32)
            int yi = (int)ys;
            bool inb = (xi >= 0) && (xi < Wn) && (yi >= 0) && (yi < Hn);
            if (inb) {
                ++cnt;
                sidx[s] = yi * Wn + xi;  // in-bounds: no clamp needed
            } else {
                sidx[s] = -0x40000000;   // sentinel: never lands in any chunk
            }
        }
    } else {
#pragma unroll
        for (int s = 0; s < Sn; ++s) sidx[s] = -0x40000000;
    }

    float sum = 0.0f;
    int pos = 0;
#pragma unroll 1
    for (int ch = 0; ch < NCH; ++ch) {
        const int r0 = ch * CH_PIX;
        const float4* gx = (const float4*)(pafx + r0);
        const float4* gy = (const float4*)(pafy + r0);
        float4* lx = (float4*)sx;
        float4* ly = (float4*)sy;
#pragma unroll
        for (int k = 0; k < CH_PIX / 4 / 512; ++k) {    // 3 per map
            lx[k * 512 + tid] = gx[k * 512 + tid];
            ly[k * 512 + tid] = gy[k * 512 + tid];
        }
        __syncthreads();
#pragma unroll
        for (int s = 0; s < Sn; ++s) {
            unsigned rel = (unsigned)(sidx[s] - r0);
            if (rel < (unsigned)CH_PIX) {
                float vs = sx[rel] * vx + sy[rel] * vy;
                sum += vs;
                if (vs > 0.05f) ++pos;
            }
        }
        __syncthreads();
    }

    if (act) {
        float denom = fmaxf((float)cnt, 1.0f);
        float mean = sum / denom;
        float ratio = (float)pos / denom;
        bool ok = (cnt > 0) && (mean > 0.0f) && (ratio > 0.8f) && (sa > 0.1f) && (sb > 0.1f);
        conn[(size_t)bc * NPAIR + tid] = ok ? (mean + 0.5f * (sa + sb)) : 0.0f;
    }
}

extern "C" void kernel_launch(void* const* d_in, const int* in_sizes, int n_in,
                              void* d_out, int out_size, void* d_ws, size_t ws_size,
                              hipStream_t stream) {
    const float* heat = (const float*)d_in[0];
    const float* paf  = (const float*)d_in[1];
    float* out   = (float*)d_out;
    float* peaks = out;                    // (B,K,P,3)
    float* conn  = out + PEAKS_FLOATS;     // (B,C,P,P)
    unsigned long long* waves = (unsigned long long*)d_ws;  // 2176*4*20 u64 = 1.39 MB

    topk_strip<<<Bn * Kn * NSTRIP, 256, 0, stream>>>(heat, waves);
    topk_merge<<<Bn * Kn, 64, 0, stream>>>(heat, waves, peaks);
    conn_staged<<<Bn * Cn, 512, 0, stream>>>(paf, peaks, conn);
}